// Round 3
// baseline (810.697 us; speedup 1.0000x reference)
//
#include <hip/hip_runtime.h>

typedef unsigned short ushort_t;

#define CH 512
#define NSP 1024  // H*W

__device__ __forceinline__ float bf2f(ushort_t u) {
    union { unsigned int i; float f; } t; t.i = ((unsigned int)u) << 16; return t.f;
}
__device__ __forceinline__ ushort_t f2bf(float f) {
    union { float fl; unsigned int i; } t; t.fl = f;
    unsigned int r = t.i + 0x7fffu + ((t.i >> 16) & 1u);  // RNE
    return (ushort_t)(r >> 16);
}

// ---------------- GroupNorm: one block per (b, group); x fp32 -> xn bf16 ----------------
__global__ void gn_kernel(const float* __restrict__ x, const float* __restrict__ gw,
                          const float* __restrict__ gbias, ushort_t* __restrict__ xn) {
    int bg = blockIdx.x;            // b*32 + g
    int g  = bg & 31;
    size_t base = (size_t)bg * 16384;   // (b*512 + g*16) * 1024
    int tid = threadIdx.x;
    float s = 0.f, s2 = 0.f;
    const float4* x4 = reinterpret_cast<const float4*>(x + base);
    for (int i = tid; i < 4096; i += 256) {
        float4 v = x4[i];
        s  += v.x + v.y + v.z + v.w;
        s2 += v.x * v.x + v.y * v.y + v.z * v.z + v.w * v.w;
    }
    #pragma unroll
    for (int off = 32; off > 0; off >>= 1) {
        s  += __shfl_down(s, off, 64);
        s2 += __shfl_down(s2, off, 64);
    }
    __shared__ float red[8];
    __shared__ float stats[2];
    int wv = tid >> 6;
    if ((tid & 63) == 0) { red[wv] = s; red[4 + wv] = s2; }
    __syncthreads();
    if (tid == 0) {
        float ts  = red[0] + red[1] + red[2] + red[3];
        float ts2 = red[4] + red[5] + red[6] + red[7];
        float mu  = ts * (1.f / 16384.f);
        float var = ts2 * (1.f / 16384.f) - mu * mu;
        stats[0] = mu;
        stats[1] = rsqrtf(var + 1e-5f);
    }
    __syncthreads();
    float mu = stats[0], rstd = stats[1];
    int c0 = g * 16;
    for (int i = tid; i < 4096; i += 256) {
        int c = c0 + (i >> 8);          // 256 float4 per channel row
        float wv_ = gw[c], bv_ = gbias[c];
        float4 v = x4[i];
        ushort4 o;
        o.x = f2bf((v.x - mu) * rstd * wv_ + bv_);
        o.y = f2bf((v.y - mu) * rstd * wv_ + bv_);
        o.z = f2bf((v.z - mu) * rstd * wv_ + bv_);
        o.w = f2bf((v.w - mu) * rstd * wv_ + bv_);
        *reinterpret_cast<ushort4*>(&xn[base + (size_t)i * 4]) = o;
    }
}

// ------------- conv1x1 as per-batch GEMM: out[b,o,n] = bias[o] + sum_c w[o,c]*xin[b,c,n] -------------
// xin bf16, w/bias/resid fp32. BF16OUT selects bf16 vs fp32 output.
// block (16,16), 64x64 tile, 4x4/thread, K-tile 16.
template <bool BF16OUT>
__global__ __launch_bounds__(256) void conv_kernel(const ushort_t* __restrict__ xin,
                                                   const float* __restrict__ w,
                                                   const float* __restrict__ bias,
                                                   const float* __restrict__ resid,
                                                   void* __restrict__ outv) {
    __shared__ __align__(16) float Wt[16][68];  // [kk][oo]
    __shared__ __align__(16) float Xt[16][68];  // [kk][nn]
    int n0 = blockIdx.x * 64;
    int o0 = blockIdx.y * 64;
    int b  = blockIdx.z;
    int tx = threadIdx.x, ty = threadIdx.y;
    int tid = ty * 16 + tx;
    float acc[4][4] = {};
    const ushort_t* xb = xin + (size_t)b * CH * NSP;

    int oo  = tid >> 2;          // 0..63
    int kk4 = (tid & 3) << 2;    // 0,4,8,12
    int kk  = tid >> 4;          // 0..15
    int nn4 = (tid & 15) << 2;   // 0..60

    for (int k0 = 0; k0 < CH; k0 += 16) {
        float4 wv = *reinterpret_cast<const float4*>(&w[(size_t)(o0 + oo) * CH + k0 + kk4]);
        Wt[kk4 + 0][oo] = wv.x;
        Wt[kk4 + 1][oo] = wv.y;
        Wt[kk4 + 2][oo] = wv.z;
        Wt[kk4 + 3][oo] = wv.w;
        ushort4 xv = *reinterpret_cast<const ushort4*>(&xb[(size_t)(k0 + kk) * NSP + n0 + nn4]);
        *reinterpret_cast<float4*>(&Xt[kk][nn4]) =
            make_float4(bf2f(xv.x), bf2f(xv.y), bf2f(xv.z), bf2f(xv.w));
        __syncthreads();
        #pragma unroll
        for (int q = 0; q < 16; q++) {
            float4 ra = *reinterpret_cast<const float4*>(&Wt[q][ty * 4]);
            float4 rb = *reinterpret_cast<const float4*>(&Xt[q][tx * 4]);
            acc[0][0] += ra.x * rb.x; acc[0][1] += ra.x * rb.y; acc[0][2] += ra.x * rb.z; acc[0][3] += ra.x * rb.w;
            acc[1][0] += ra.y * rb.x; acc[1][1] += ra.y * rb.y; acc[1][2] += ra.y * rb.z; acc[1][3] += ra.y * rb.w;
            acc[2][0] += ra.z * rb.x; acc[2][1] += ra.z * rb.y; acc[2][2] += ra.z * rb.z; acc[2][3] += ra.z * rb.w;
            acc[3][0] += ra.w * rb.x; acc[3][1] += ra.w * rb.y; acc[3][2] += ra.w * rb.z; acc[3][3] += ra.w * rb.w;
        }
        __syncthreads();
    }
    #pragma unroll
    for (int a = 0; a < 4; a++) {
        int o = o0 + ty * 4 + a;
        float bv = bias[o];
        size_t rowbase = ((size_t)b * CH + o) * NSP;
        #pragma unroll
        for (int c = 0; c < 4; c++) {
            int n = n0 + tx * 4 + c;
            float r = acc[a][c] + bv;
            if (resid) r += resid[rowbase + n];
            if (BF16OUT) {
                ((ushort_t*)outv)[rowbase + n] = f2bf(r);
            } else {
                ((float*)outv)[rowbase + n] = r;
            }
        }
    }
}

// ------------- flash-style attention: block = (64 queries, 4), one (b,h,i-tile) per block -------------
// q/k/v bf16, ao bf16 (ao may alias q: each block reads only its own q tile at start,
// writes the same region at end; regions are disjoint across blocks).
__global__ __launch_bounds__(256) void attn_kernel(const ushort_t* __restrict__ q,
                                                   const ushort_t* __restrict__ k,
                                                   const ushort_t* __restrict__ v,
                                                   ushort_t* __restrict__ ao) {
    __shared__ __align__(16) float ks[64][68];  // [j][dd]
    __shared__ __align__(16) float vs[64][68];  // [j][dd]
    __shared__ float ps[64][65];                // [i][j] exp'd probs
    __shared__ float pmx[4][64];
    __shared__ float psm[4][64];
    int it = blockIdx.x;
    int bh = blockIdx.y;                        // b*8 + h
    size_t base = (size_t)bh * 64 * NSP;        // (b*512 + h*64)*1024
    int tx = threadIdx.x;                       // query i within tile
    int ty = threadIdx.y;                       // 0..3
    int tid = ty * 64 + tx;
    int i = it * 64 + tx;
    const float scale = 0.125f;                 // 1/sqrt(64)

    float qreg[64];
    #pragma unroll
    for (int dd = 0; dd < 64; dd++)
        qreg[dd] = bf2f(q[base + (size_t)dd * NSP + i]);

    float oacc[16];
    #pragma unroll
    for (int r = 0; r < 16; r++) oacc[r] = 0.f;
    float m = -1e30f, l = 0.f;

    int lj4 = (tid & 15) << 2;   // 0..60
    int ld0 = tid >> 4;          // 0..15

    for (int jt = 0; jt < 16; jt++) {
        // --- load K/V tile (coalesced over j; LDS layout [j][dd]) ---
        #pragma unroll
        for (int t = 0; t < 4; t++) {
            int dd = ld0 + t * 16;
            size_t goff = base + (size_t)dd * NSP + jt * 64 + lj4;
            ushort4 kv = *reinterpret_cast<const ushort4*>(&k[goff]);
            ushort4 vv = *reinterpret_cast<const ushort4*>(&v[goff]);
            ks[lj4 + 0][dd] = bf2f(kv.x);
            ks[lj4 + 1][dd] = bf2f(kv.y);
            ks[lj4 + 2][dd] = bf2f(kv.z);
            ks[lj4 + 3][dd] = bf2f(kv.w);
            vs[lj4 + 0][dd] = bf2f(vv.x);
            vs[lj4 + 1][dd] = bf2f(vv.y);
            vs[lj4 + 2][dd] = bf2f(vv.z);
            vs[lj4 + 3][dd] = bf2f(vv.w);
        }
        __syncthreads();

        // --- S = q . k, each thread: i=tx, j in [16ty, 16ty+16) ---
        float sv[16];
        float mloc = -1e30f;
        #pragma unroll
        for (int jj = 0; jj < 16; jj++) {
            int j = ty * 16 + jj;
            const float4* krow = reinterpret_cast<const float4*>(&ks[j][0]);
            float a = 0.f;
            #pragma unroll
            for (int t = 0; t < 16; t++) {
                float4 kv = krow[t];
                a += qreg[4 * t + 0] * kv.x + qreg[4 * t + 1] * kv.y
                   + qreg[4 * t + 2] * kv.z + qreg[4 * t + 3] * kv.w;
            }
            sv[jj] = a * scale;
            mloc = fmaxf(mloc, sv[jj]);
        }
        pmx[ty][tx] = mloc;
        __syncthreads();

        // --- online softmax update ---
        float tmax = fmaxf(fmaxf(pmx[0][tx], pmx[1][tx]), fmaxf(pmx[2][tx], pmx[3][tx]));
        float mnew = fmaxf(m, tmax);
        float alpha = __expf(m - mnew);
        m = mnew;
        float psum = 0.f;
        #pragma unroll
        for (int jj = 0; jj < 16; jj++) {
            float p = __expf(sv[jj] - mnew);
            ps[tx][ty * 16 + jj] = p;
            psum += p;
        }
        psm[ty][tx] = psum;
        __syncthreads();

        float rowsum = psm[0][tx] + psm[1][tx] + psm[2][tx] + psm[3][tx];
        l = l * alpha + rowsum;
        #pragma unroll
        for (int r = 0; r < 16; r++) oacc[r] *= alpha;

        // --- PV: oacc[dd=16ty+r][i=tx] += p[i][j] * v[dd][j] ---
        for (int j = 0; j < 64; j++) {
            float p = ps[tx][j];
            const float4* vrow = reinterpret_cast<const float4*>(&vs[j][ty * 16]);
            float4 v0 = vrow[0], v1 = vrow[1], v2 = vrow[2], v3 = vrow[3];
            oacc[0]  += p * v0.x; oacc[1]  += p * v0.y; oacc[2]  += p * v0.z; oacc[3]  += p * v0.w;
            oacc[4]  += p * v1.x; oacc[5]  += p * v1.y; oacc[6]  += p * v1.z; oacc[7]  += p * v1.w;
            oacc[8]  += p * v2.x; oacc[9]  += p * v2.y; oacc[10] += p * v2.z; oacc[11] += p * v2.w;
            oacc[12] += p * v3.x; oacc[13] += p * v3.y; oacc[14] += p * v3.z; oacc[15] += p * v3.w;
        }
        __syncthreads();
    }

    float linv = 1.f / l;
    #pragma unroll
    for (int r = 0; r < 16; r++) {
        int dd = ty * 16 + r;
        ao[base + (size_t)dd * NSP + i] = f2bf(oacc[r] * linv);
    }
}

extern "C" void kernel_launch(void* const* d_in, const int* in_sizes, int n_in,
                              void* d_out, int out_size, void* d_ws, size_t ws_size,
                              hipStream_t stream) {
    const float* x    = (const float*)d_in[0];
    const float* gn_w = (const float*)d_in[1];
    const float* gn_b = (const float*)d_in[2];
    const float* wq   = (const float*)d_in[3];
    const float* bq   = (const float*)d_in[4];
    const float* wk   = (const float*)d_in[5];
    const float* bk   = (const float*)d_in[6];
    const float* wv   = (const float*)d_in[7];
    const float* bv   = (const float*)d_in[8];
    const float* wo   = (const float*)d_in[9];
    const float* bo   = (const float*)d_in[10];

    const size_t elems = (size_t)8 * CH * NSP;  // 4,194,304
    ushort_t* xn = (ushort_t*)d_ws;
    ushort_t* qb = xn + elems;
    ushort_t* kb = qb + elems;
    ushort_t* vb = kb + elems;
    ushort_t* ob = qb;   // attention output aliases q (safe: disjoint per-block r/w regions)

    gn_kernel<<<256, 256, 0, stream>>>(x, gn_w, gn_b, xn);

    dim3 cgrid(NSP / 64, CH / 64, 8);
    dim3 cblk(16, 16);
    conv_kernel<true><<<cgrid, cblk, 0, stream>>>(xn, wq, bq, nullptr, (void*)qb);
    conv_kernel<true><<<cgrid, cblk, 0, stream>>>(xn, wk, bk, nullptr, (void*)kb);
    conv_kernel<true><<<cgrid, cblk, 0, stream>>>(xn, wv, bv, nullptr, (void*)vb);

    attn_kernel<<<dim3(NSP / 64, 64), dim3(64, 4), 0, stream>>>(qb, kb, vb, ob);

    conv_kernel<false><<<cgrid, cblk, 0, stream>>>(ob, wo, bo, x, d_out);
}

// Round 5
// 209.919 us; speedup vs baseline: 3.8620x; 3.8620x over previous
//
#include <hip/hip_runtime.h>

typedef unsigned short ushort_t;
typedef __bf16 bf16_t;
typedef bf16_t bf16x8 __attribute__((ext_vector_type(8)));
typedef float f32x4 __attribute__((ext_vector_type(4)));

#define CH 512
#define NSP 1024  // H*W

__device__ __forceinline__ float bf2f(ushort_t u) {
    union { unsigned int i; float f; } t; t.i = ((unsigned int)u) << 16; return t.f;
}
__device__ __forceinline__ ushort_t f2bf(float f) {
    union { float fl; unsigned int i; } t; t.fl = f;
    unsigned int r = t.i + 0x7fffu + ((t.i >> 16) & 1u);  // RNE
    return (ushort_t)(r >> 16);
}

// async 16B global->LDS copy (m97 pattern). LDS dest must be wave-uniform base + lane*16.
#if __has_builtin(__builtin_amdgcn_global_load_lds)
#define HAVE_ASYNC_LDS 1
#endif
__device__ __forceinline__ void cp16(const ushort_t* g, ushort_t* l) {
#ifdef HAVE_ASYNC_LDS
    __builtin_amdgcn_global_load_lds((const __attribute__((address_space(1))) unsigned int*)g,
                                     (__attribute__((address_space(3))) unsigned int*)l, 16, 0, 0);
#else
    *(uint4*)l = *(const uint4*)g;
#endif
}

// ---------------- W fp32 -> bf16 pre-convert (4 matrices of 512x512) ----------------
__global__ __launch_bounds__(256) void wcvt_kernel(const float* __restrict__ w0, const float* __restrict__ w1,
                                                   const float* __restrict__ w2, const float* __restrict__ w3,
                                                   ushort_t* __restrict__ dst) {
    const float* src = (blockIdx.y == 0) ? w0 : (blockIdx.y == 1) ? w1 : (blockIdx.y == 2) ? w2 : w3;
    ushort_t* d = dst + (size_t)blockIdx.y * 262144;
    int idx = blockIdx.x * 256 + threadIdx.x;      // 0..65535 float4s
    float4 v = reinterpret_cast<const float4*>(src)[idx];
    ushort4 u;
    u.x = f2bf(v.x); u.y = f2bf(v.y); u.z = f2bf(v.z); u.w = f2bf(v.w);
    reinterpret_cast<ushort4*>(d)[idx] = u;
}

// ---------------- GroupNorm: block per (b,g); x fp32 [b][c][n] -> xn_t bf16 [b][n][c] ----------------
__global__ __launch_bounds__(256) void gn_kernel(const float* __restrict__ x, const float* __restrict__ gw,
                                                 const float* __restrict__ gbias, ushort_t* __restrict__ xnt) {
    __shared__ __align__(16) ushort_t lx[16 * 1024];   // bf16 copy of the group's 16x1024 slab
    __shared__ float red[8];
    __shared__ float stats[2];
    int bg = blockIdx.x;            // b*32 + g
    int b  = bg >> 5, g = bg & 31;
    size_t base = (size_t)bg * 16384;
    int tid = threadIdx.x;
    float s = 0.f, s2 = 0.f;
    const float4* x4 = reinterpret_cast<const float4*>(x + base);
    for (int i = tid; i < 4096; i += 256) {
        float4 v = x4[i];
        s  += v.x + v.y + v.z + v.w;
        s2 += v.x * v.x + v.y * v.y + v.z * v.z + v.w * v.w;
        ushort4 u;
        u.x = f2bf(v.x); u.y = f2bf(v.y); u.z = f2bf(v.z); u.w = f2bf(v.w);
        *reinterpret_cast<ushort4*>(&lx[i * 4]) = u;
    }
    #pragma unroll
    for (int off = 32; off > 0; off >>= 1) {
        s  += __shfl_down(s, off, 64);
        s2 += __shfl_down(s2, off, 64);
    }
    int wv = tid >> 6;
    if ((tid & 63) == 0) { red[wv] = s; red[4 + wv] = s2; }
    __syncthreads();
    if (tid == 0) {
        float ts  = red[0] + red[1] + red[2] + red[3];
        float ts2 = red[4] + red[5] + red[6] + red[7];
        float mu  = ts * (1.f / 16384.f);
        float var = ts2 * (1.f / 16384.f) - mu * mu;
        stats[0] = mu;
        stats[1] = rsqrtf(var + 1e-5f);
    }
    __syncthreads();
    float mu = stats[0], rstd = stats[1];
    float ca[16], cb[16];
    #pragma unroll
    for (int c = 0; c < 16; c++) {
        float wv_ = gw[g * 16 + c], bb = gbias[g * 16 + c];
        ca[c] = rstd * wv_;
        cb[c] = bb - mu * rstd * wv_;
    }
    // transpose write: xn_t[b][n][g*16 + c]
    for (int rep = 0; rep < 4; rep++) {
        int n = rep * 256 + tid;
        ushort_t ov[16];
        #pragma unroll
        for (int c = 0; c < 16; c++) {
            float v = bf2f(lx[c * 1024 + n]);
            ov[c] = f2bf(v * ca[c] + cb[c]);
        }
        ushort_t* dst = xnt + ((size_t)(b * 1024 + n)) * 512 + g * 16;
        *reinterpret_cast<ushort4*>(dst + 0)  = *reinterpret_cast<ushort4*>(&ov[0]);
        *reinterpret_cast<ushort4*>(dst + 4)  = *reinterpret_cast<ushort4*>(&ov[4]);
        *reinterpret_cast<ushort4*>(dst + 8)  = *reinterpret_cast<ushort4*>(&ov[8]);
        *reinterpret_cast<ushort4*>(dst + 12) = *reinterpret_cast<ushort4*>(&ov[12]);
    }
}

// ---------------- MFMA conv1x1 ----------------
// ORIENT 0: C[m=n_sp][n=o]   A=xn_t rows n_sp, B=W rows o. out = q_t/k_t [b][h][n][d] bf16.
// ORIENT 1: C[m=o][n=n_sp]   A=W rows o, B=xn_t rows n_sp. out = v [b][o][n] bf16.
// ORIENT 2: like 1, fp32 out + bias + residual x.
// M-tile 128, N-tile 64, BK 32. 4 waves as 2x2 (wave tile 64x32 = 4x2 MFMA frags).
template <int ORIENT>
__global__ __launch_bounds__(256) void conv_mfma(const ushort_t* __restrict__ xnt,
                                                 const ushort_t* __restrict__ wb,
                                                 const float* __restrict__ bias,
                                                 const float* __restrict__ xres,
                                                 void* __restrict__ out) {
    __shared__ __align__(16) char smem[(ORIENT == 2) ? 32768 : 16384];
    ushort_t* als = (ushort_t*)smem;           // [128][32] bf16 = 8KB
    ushort_t* bls = (ushort_t*)(smem + 8192);  // [64][32]  bf16 = 4KB

    int tid = threadIdx.x;
    int wave = tid >> 6, lane = tid & 63, l15 = lane & 15, quad = lane >> 4;
    int wm = wave >> 1, wn = wave & 1;
    int m0 = blockIdx.x * 128, n0 = blockIdx.y * 64, b = blockIdx.z;

    const ushort_t* aptr = (ORIENT == 0) ? xnt + (size_t)b * 524288 : wb;
    const ushort_t* bptr = (ORIENT == 0) ? wb : xnt + (size_t)b * 524288;

    f32x4 acc[4][2];
    #pragma unroll
    for (int ms = 0; ms < 4; ms++)
        #pragma unroll
        for (int ns = 0; ns < 2; ns++) acc[ms][ns] = (f32x4){0.f, 0.f, 0.f, 0.f};

    for (int k0 = 0; k0 < 512; k0 += 32) {
        #pragma unroll
        for (int rep = 0; rep < 2; rep++) {
            int id = rep * 256 + tid;
            int r = id >> 2, part = id & 3;
            cp16(aptr + (size_t)(m0 + r) * 512 + k0 + part * 8, als + (size_t)id * 8);
        }
        {
            int r = tid >> 2, part = tid & 3;
            cp16(bptr + (size_t)(n0 + r) * 512 + k0 + part * 8, bls + (size_t)tid * 8);
        }
        __syncthreads();
        bf16x8 af[4], bfr[2];
        #pragma unroll
        for (int ms = 0; ms < 4; ms++)
            af[ms] = *(const bf16x8*)(als + (wm * 64 + ms * 16 + l15) * 32 + quad * 8);
        #pragma unroll
        for (int ns = 0; ns < 2; ns++)
            bfr[ns] = *(const bf16x8*)(bls + (wn * 32 + ns * 16 + l15) * 32 + quad * 8);
        #pragma unroll
        for (int ms = 0; ms < 4; ms++)
            #pragma unroll
            for (int ns = 0; ns < 2; ns++)
                acc[ms][ns] = __builtin_amdgcn_mfma_f32_16x16x32_bf16(af[ms], bfr[ns], acc[ms][ns], 0, 0, 0);
        __syncthreads();
    }

    // ---- epilogue: frags -> LDS -> coalesced global ----
    if (ORIENT == 0) {
        float bv[2];
        bv[0] = bias[n0 + wn * 32 + l15];
        bv[1] = bias[n0 + wn * 32 + 16 + l15];
        ushort_t* cls = (ushort_t*)smem;   // [128 rows=n_sp][64 cols=o]
        #pragma unroll
        for (int ms = 0; ms < 4; ms++)
            #pragma unroll
            for (int ns = 0; ns < 2; ns++)
                #pragma unroll
                for (int r = 0; r < 4; r++)
                    cls[(wm * 64 + ms * 16 + quad * 4 + r) * 64 + wn * 32 + ns * 16 + l15] =
                        f2bf(acc[ms][ns][r] + bv[ns]);
        __syncthreads();
        ushort_t* qt = (ushort_t*)out;
        int h = n0 >> 6;
        size_t obase = ((size_t)(b * 8 + h) * 1024 + m0) * 64;
        #pragma unroll
        for (int rep = 0; rep < 4; rep++) {
            int id = rep * 256 + tid;
            int r = id >> 3, part = id & 7;
            *(uint4*)(qt + obase + (size_t)r * 64 + part * 8) = *(const uint4*)(cls + r * 64 + part * 8);
        }
    } else if (ORIENT == 1) {
        ushort_t* cls = (ushort_t*)smem;   // [128 rows=o][64 cols=n_sp]
        #pragma unroll
        for (int ms = 0; ms < 4; ms++)
            #pragma unroll
            for (int ns = 0; ns < 2; ns++)
                #pragma unroll
                for (int r = 0; r < 4; r++)
                    cls[(wm * 64 + ms * 16 + quad * 4 + r) * 64 + wn * 32 + ns * 16 + l15] =
                        f2bf(acc[ms][ns][r]);
        __syncthreads();
        ushort_t* vt = (ushort_t*)out;
        #pragma unroll
        for (int rep = 0; rep < 4; rep++) {
            int id = rep * 256 + tid;
            int r = id >> 3, part = id & 7;
            float bvr = bias[m0 + r];
            ushort4 ua = *(const ushort4*)(cls + r * 64 + part * 8);
            ushort4 ub = *(const ushort4*)(cls + r * 64 + part * 8 + 4);
            ua.x = f2bf(bf2f(ua.x) + bvr); ua.y = f2bf(bf2f(ua.y) + bvr);
            ua.z = f2bf(bf2f(ua.z) + bvr); ua.w = f2bf(bf2f(ua.w) + bvr);
            ub.x = f2bf(bf2f(ub.x) + bvr); ub.y = f2bf(bf2f(ub.y) + bvr);
            ub.z = f2bf(bf2f(ub.z) + bvr); ub.w = f2bf(bf2f(ub.w) + bvr);
            ushort_t* dst = vt + ((size_t)b * 512 + m0 + r) * 1024 + n0 + part * 8;
            *(ushort4*)dst = ua;
            *(ushort4*)(dst + 4) = ub;
        }
    } else {
        float* clsf = (float*)smem;        // [128 rows=o][64 cols=n_sp] fp32 = 32KB
        #pragma unroll
        for (int ms = 0; ms < 4; ms++)
            #pragma unroll
            for (int ns = 0; ns < 2; ns++)
                #pragma unroll
                for (int r = 0; r < 4; r++)
                    clsf[(wm * 64 + ms * 16 + quad * 4 + r) * 64 + wn * 32 + ns * 16 + l15] =
                        acc[ms][ns][r];
        __syncthreads();
        float* of = (float*)out;
        #pragma unroll
        for (int rep = 0; rep < 8; rep++) {
            int id = rep * 256 + tid;
            int r = id >> 4, part = id & 15;
            float bvr = bias[m0 + r];
            float4 c4 = *(const float4*)(clsf + r * 64 + part * 4);
            size_t ga = ((size_t)b * 512 + m0 + r) * 1024 + n0 + part * 4;
            float4 xv = *(const float4*)(xres + ga);
            c4.x += bvr + xv.x; c4.y += bvr + xv.y; c4.z += bvr + xv.z; c4.w += bvr + xv.w;
            *(float4*)(of + ga) = c4;
        }
    }
}

// ---------------- MFMA flash attention ----------------
// q_t/k_t: [bh][n][d] bf16 (d contig). v: [bh][d][n] bf16 (n contig). ao: [b][n][c] bf16.
// Block: 256 thr = 4 waves; i-tile 64 (16 per wave), j-tiles of 64, d = 64.
__global__ __launch_bounds__(256) void attn_kernel(const ushort_t* __restrict__ qt,
                                                   const ushort_t* __restrict__ kt,
                                                   const ushort_t* __restrict__ vt,
                                                   ushort_t* __restrict__ ao) {
    __shared__ __align__(16) ushort_t kls[64 * 72];   // row j, stride 72 (144B, conflict-free for b128)
    __shared__ __align__(16) ushort_t vls[64 * 72];   // row d, cols j
    __shared__ __align__(16) ushort_t pls[64 * 72];   // row i, cols j (wave-private 16-row bands)
    int tid = threadIdx.x;
    int wave = tid >> 6, lane = tid & 63, l15 = lane & 15, quad = lane >> 4;
    int i0 = blockIdx.x * 64;
    int bh = blockIdx.y;
    const ushort_t* qb = qt + (size_t)bh * 65536;
    const ushort_t* kb = kt + (size_t)bh * 65536;
    const ushort_t* vb = vt + (size_t)bh * 65536;
    int iw = wave * 16;
    const float SC = 0.18033688f;   // (1/8) * log2(e)

    bf16x8 qf0 = *(const bf16x8*)(qb + (size_t)(i0 + iw + l15) * 64 + quad * 8);
    bf16x8 qf1 = *(const bf16x8*)(qb + (size_t)(i0 + iw + l15) * 64 + 32 + quad * 8);

    f32x4 oacc[4];
    #pragma unroll
    for (int ds = 0; ds < 4; ds++) oacc[ds] = (f32x4){0.f, 0.f, 0.f, 0.f};
    float mst[4], lst[4];
    #pragma unroll
    for (int r = 0; r < 4; r++) { mst[r] = -3.0e38f; lst[r] = 0.f; }

    for (int jt = 0; jt < 16; jt++) {
        int j0 = jt * 64;
        #pragma unroll
        for (int rep = 0; rep < 2; rep++) {
            int id = rep * 256 + tid;
            int rl = id >> 3, part = id & 7;
            *(uint4*)(kls + rl * 72 + part * 8) = *(const uint4*)(kb + (size_t)(j0 + rl) * 64 + part * 8);
            *(uint4*)(vls + rl * 72 + part * 8) = *(const uint4*)(vb + (size_t)rl * 1024 + j0 + part * 8);
        }
        __syncthreads();

        // S = Q K^T for wave's 16 i x 64 j
        float t[4][4];
        #pragma unroll
        for (int js = 0; js < 4; js++) {
            bf16x8 kf0 = *(const bf16x8*)(kls + (js * 16 + l15) * 72 + quad * 8);
            bf16x8 kf1 = *(const bf16x8*)(kls + (js * 16 + l15) * 72 + 32 + quad * 8);
            f32x4 z = (f32x4){0.f, 0.f, 0.f, 0.f};
            z = __builtin_amdgcn_mfma_f32_16x16x32_bf16(qf0, kf0, z, 0, 0, 0);
            z = __builtin_amdgcn_mfma_f32_16x16x32_bf16(qf1, kf1, z, 0, 0, 0);
            #pragma unroll
            for (int r = 0; r < 4; r++) t[js][r] = z[r] * SC;
        }
        // online softmax (row i = quad*4+r; j spread over 16-lane group + js)
        float alpha[4];
        #pragma unroll
        for (int r = 0; r < 4; r++) {
            float rmax = fmaxf(fmaxf(t[0][r], t[1][r]), fmaxf(t[2][r], t[3][r]));
            #pragma unroll
            for (int off = 8; off > 0; off >>= 1) rmax = fmaxf(rmax, __shfl_xor(rmax, off, 16));
            float mn = fmaxf(mst[r], rmax);
            alpha[r] = exp2f(mst[r] - mn);
            mst[r] = mn;
        }
        float p[4][4];
        #pragma unroll
        for (int js = 0; js < 4; js++)
            #pragma unroll
            for (int r = 0; r < 4; r++) p[js][r] = exp2f(t[js][r] - mst[r]);
        #pragma unroll
        for (int r = 0; r < 4; r++) {
            float srow = p[0][r] + p[1][r] + p[2][r] + p[3][r];
            #pragma unroll
            for (int off = 8; off > 0; off >>= 1) srow += __shfl_xor(srow, off, 16);
            lst[r] = lst[r] * alpha[r] + srow;
        }
        #pragma unroll
        for (int ds = 0; ds < 4; ds++)
            #pragma unroll
            for (int r = 0; r < 4; r++) oacc[ds][r] *= alpha[r];
        // P -> LDS (wave-private rows), then PV
        #pragma unroll
        for (int js = 0; js < 4; js++)
            #pragma unroll
            for (int r = 0; r < 4; r++)
                pls[(iw + quad * 4 + r) * 72 + js * 16 + l15] = f2bf(p[js][r]);
        bf16x8 pa0 = *(const bf16x8*)(pls + (iw + l15) * 72 + quad * 8);
        bf16x8 pa1 = *(const bf16x8*)(pls + (iw + l15) * 72 + 32 + quad * 8);
        #pragma unroll
        for (int ds = 0; ds < 4; ds++) {
            bf16x8 vf0 = *(const bf16x8*)(vls + (ds * 16 + l15) * 72 + quad * 8);
            bf16x8 vf1 = *(const bf16x8*)(vls + (ds * 16 + l15) * 72 + 32 + quad * 8);
            oacc[ds] = __builtin_amdgcn_mfma_f32_16x16x32_bf16(pa0, vf0, oacc[ds], 0, 0, 0);
            oacc[ds] = __builtin_amdgcn_mfma_f32_16x16x32_bf16(pa1, vf1, oacc[ds], 0, 0, 0);
        }
        __syncthreads();
    }

    // epilogue: O/l -> LDS (reuse kls) -> coalesced ao write [b][i][h*64+d]
    float linv[4];
    #pragma unroll
    for (int r = 0; r < 4; r++) linv[r] = 1.f / lst[r];
    #pragma unroll
    for (int ds = 0; ds < 4; ds++)
        #pragma unroll
        for (int r = 0; r < 4; r++)
            kls[(iw + quad * 4 + r) * 72 + ds * 16 + l15] = f2bf(oacc[ds][r] * linv[r]);
    __syncthreads();
    int b = bh >> 3, h = bh & 7;
    ushort_t* aob = ao + ((size_t)b * 1024 + i0) * 512 + h * 64;
    #pragma unroll
    for (int rep = 0; rep < 2; rep++) {
        int id = rep * 256 + tid;
        int rl = id >> 3, part = id & 7;
        *(uint4*)(aob + (size_t)rl * 512 + part * 8) = *(const uint4*)(kls + rl * 72 + part * 8);
    }
}

extern "C" void kernel_launch(void* const* d_in, const int* in_sizes, int n_in,
                              void* d_out, int out_size, void* d_ws, size_t ws_size,
                              hipStream_t stream) {
    const float* x    = (const float*)d_in[0];
    const float* gn_w = (const float*)d_in[1];
    const float* gn_b = (const float*)d_in[2];
    const float* wq   = (const float*)d_in[3];
    const float* bq   = (const float*)d_in[4];
    const float* wk   = (const float*)d_in[5];
    const float* bk   = (const float*)d_in[6];
    const float* wv   = (const float*)d_in[7];
    const float* bv   = (const float*)d_in[8];
    const float* wo   = (const float*)d_in[9];
    const float* bo   = (const float*)d_in[10];

    char* ws = (char*)d_ws;
    ushort_t* xnt = (ushort_t*)(ws);                       // 8 MB  [b][n][c] bf16
    ushort_t* qt  = (ushort_t*)(ws + (((size_t)8)  << 20));  // 8 MB  [bh][n][d]
    ushort_t* kt  = (ushort_t*)(ws + (((size_t)16) << 20));  // 8 MB  [bh][n][d]
    ushort_t* vt  = (ushort_t*)(ws + (((size_t)24) << 20));  // 8 MB  [bh][d][n]
    ushort_t* wbf = (ushort_t*)(ws + (((size_t)32) << 20));  // 2 MB  4x 512x512 bf16
    ushort_t* ao  = xnt;  // attention output reuses xn_t (convs read xnt before attn runs)

    wcvt_kernel<<<dim3(256, 4), 256, 0, stream>>>(wq, wk, wv, wo, wbf);
    gn_kernel<<<256, 256, 0, stream>>>(x, gn_w, gn_b, xnt);

    conv_mfma<0><<<dim3(8, 8, 8),  256, 0, stream>>>(xnt, wbf + 0,      bq, nullptr, (void*)qt);
    conv_mfma<0><<<dim3(8, 8, 8),  256, 0, stream>>>(xnt, wbf + 262144, bk, nullptr, (void*)kt);
    conv_mfma<1><<<dim3(4, 16, 8), 256, 0, stream>>>(xnt, wbf + 524288, bv, nullptr, (void*)vt);

    attn_kernel<<<dim3(16, 64), 256, 0, stream>>>(qt, kt, vt, ao);

    conv_mfma<2><<<dim3(4, 16, 8), 256, 0, stream>>>(ao, wbf + 786432, bo, x, d_out);
}

// Round 6
// 180.494 us; speedup vs baseline: 4.4916x; 1.1630x over previous
//
#include <hip/hip_runtime.h>

typedef unsigned short ushort_t;
typedef __bf16 bf16_t;
typedef bf16_t bf16x8 __attribute__((ext_vector_type(8)));
typedef float f32x4 __attribute__((ext_vector_type(4)));

#define CH 512
#define NSP 1024  // H*W

__device__ __forceinline__ float bf2f(ushort_t u) {
    union { unsigned int i; float f; } t; t.i = ((unsigned int)u) << 16; return t.f;
}
__device__ __forceinline__ ushort_t f2bf(float f) {
    union { float fl; unsigned int i; } t; t.fl = f;
    unsigned int r = t.i + 0x7fffu + ((t.i >> 16) & 1u);  // RNE
    return (ushort_t)(r >> 16);
}

#if __has_builtin(__builtin_amdgcn_global_load_lds)
#define HAVE_ASYNC_LDS 1
#endif
__device__ __forceinline__ void cp16(const ushort_t* g, ushort_t* l) {
#ifdef HAVE_ASYNC_LDS
    __builtin_amdgcn_global_load_lds((const __attribute__((address_space(1))) unsigned int*)g,
                                     (__attribute__((address_space(3))) unsigned int*)l, 16, 0, 0);
#else
    *(uint4*)l = *(const uint4*)g;
#endif
}

// ---------------- W fp32 -> bf16 pre-convert (Wq|Wk|Wv|Wo concatenated) ----------------
__global__ __launch_bounds__(256) void wcvt_kernel(const float* __restrict__ w0, const float* __restrict__ w1,
                                                   const float* __restrict__ w2, const float* __restrict__ w3,
                                                   ushort_t* __restrict__ dst) {
    const float* src = (blockIdx.y == 0) ? w0 : (blockIdx.y == 1) ? w1 : (blockIdx.y == 2) ? w2 : w3;
    ushort_t* d = dst + (size_t)blockIdx.y * 262144;
    int idx = blockIdx.x * 256 + threadIdx.x;
    float4 v = reinterpret_cast<const float4*>(src)[idx];
    ushort4 u;
    u.x = f2bf(v.x); u.y = f2bf(v.y); u.z = f2bf(v.z); u.w = f2bf(v.w);
    reinterpret_cast<ushort4*>(d)[idx] = u;
}

// ---------------- GroupNorm phase A: stats per (b,g) ----------------
__global__ __launch_bounds__(256) void gn_stats(const float* __restrict__ x, float2* __restrict__ gstats) {
    __shared__ float red[8];
    int bg = blockIdx.x;
    size_t base = (size_t)bg * 16384;
    int tid = threadIdx.x;
    float s = 0.f, s2 = 0.f;
    const float4* x4 = reinterpret_cast<const float4*>(x + base);
    for (int i = tid; i < 4096; i += 256) {
        float4 v = x4[i];
        s  += v.x + v.y + v.z + v.w;
        s2 += v.x * v.x + v.y * v.y + v.z * v.z + v.w * v.w;
    }
    #pragma unroll
    for (int off = 32; off > 0; off >>= 1) {
        s  += __shfl_down(s, off, 64);
        s2 += __shfl_down(s2, off, 64);
    }
    int wv = tid >> 6;
    if ((tid & 63) == 0) { red[wv] = s; red[4 + wv] = s2; }
    __syncthreads();
    if (tid == 0) {
        float ts  = red[0] + red[1] + red[2] + red[3];
        float ts2 = red[4] + red[5] + red[6] + red[7];
        float mu  = ts * (1.f / 16384.f);
        float var = ts2 * (1.f / 16384.f) - mu * mu;
        gstats[bg] = make_float2(mu, rsqrtf(var + 1e-5f));
    }
}

// ---------------- GroupNorm phase B: apply + transpose -> xnt [b][n][c] bf16 ----------------
__global__ __launch_bounds__(256) void gn_apply(const float* __restrict__ x, const float* __restrict__ gw,
                                                const float* __restrict__ gbias, const float2* __restrict__ gstats,
                                                ushort_t* __restrict__ xnt) {
    __shared__ __align__(16) ushort_t lt[16 * 264];
    int nq = blockIdx.x;            // 0..3 (256-col chunk)
    int bg = blockIdx.y;            // b*32+g
    int b = bg >> 5, g = bg & 31;
    int tid = threadIdx.x;
    float2 st = gstats[bg];
    float mu = st.x, rstd = st.y;
    const float4* x4 = reinterpret_cast<const float4*>(x + ((size_t)(b * 512 + g * 16) * 1024 + nq * 256));
    #pragma unroll
    for (int rep = 0; rep < 4; rep++) {
        int id = rep * 256 + tid;
        int cc = id >> 6, j = id & 63;   // row cc, float4 j (x4 row stride = 256 float4s)
        float ww = gw[g * 16 + cc], bb = gbias[g * 16 + cc];
        float ca = rstd * ww, cb = bb - mu * ca;
        float4 v = x4[cc * 256 + j];
        ushort4 u;
        u.x = f2bf(v.x * ca + cb); u.y = f2bf(v.y * ca + cb);
        u.z = f2bf(v.z * ca + cb); u.w = f2bf(v.w * ca + cb);
        *reinterpret_cast<ushort4*>(&lt[cc * 264 + j * 4]) = u;
    }
    __syncthreads();
    int n = tid;   // 0..255
    ushort_t ov[16];
    #pragma unroll
    for (int cc = 0; cc < 16; cc++) ov[cc] = lt[cc * 264 + n];
    ushort_t* dst = xnt + ((size_t)(b * 1024 + nq * 256 + n)) * 512 + g * 16;
    *reinterpret_cast<ushort4*>(dst + 0)  = *reinterpret_cast<ushort4*>(&ov[0]);
    *reinterpret_cast<ushort4*>(dst + 4)  = *reinterpret_cast<ushort4*>(&ov[4]);
    *reinterpret_cast<ushort4*>(dst + 8)  = *reinterpret_cast<ushort4*>(&ov[8]);
    *reinterpret_cast<ushort4*>(dst + 12) = *reinterpret_cast<ushort4*>(&ov[12]);
}

// ---------------- Fused QKV conv: C[n_sp(128)][o(64)] tiles over o in 0..1535 ----------------
// A = xnt[b] rows n_sp, B = wbf rows o (Wq|Wk|Wv). Epilogue by segment:
//   o<512 -> qt[bh][n][d]; o<1024 -> kt; else vt[b][d][n] (transposed).
__global__ __launch_bounds__(256) void conv_qkv(const ushort_t* __restrict__ xnt,
                                                const ushort_t* __restrict__ wbf,
                                                const float* __restrict__ bq,
                                                const float* __restrict__ bk,
                                                const float* __restrict__ bv,
                                                ushort_t* __restrict__ qt,
                                                ushort_t* __restrict__ kt,
                                                ushort_t* __restrict__ vt) {
    __shared__ __align__(16) char smem[17408];
    ushort_t* als = (ushort_t*)smem;           // [128][32]
    ushort_t* bls = (ushort_t*)(smem + 8192);  // [64][32]
    int tid = threadIdx.x;
    int wave = tid >> 6, lane = tid & 63, l15 = lane & 15, quad = lane >> 4;
    int wm = wave >> 1, wn = wave & 1;
    int m0 = blockIdx.x * 128, o0 = blockIdx.y * 64, b = blockIdx.z;
    const ushort_t* A = xnt + (size_t)b * 524288;

    f32x4 acc[4][2];
    #pragma unroll
    for (int ms = 0; ms < 4; ms++)
        #pragma unroll
        for (int ns = 0; ns < 2; ns++) acc[ms][ns] = (f32x4){0.f, 0.f, 0.f, 0.f};

    for (int k0 = 0; k0 < 512; k0 += 32) {
        #pragma unroll
        for (int rep = 0; rep < 2; rep++) {
            int id = rep * 256 + tid;
            int r = id >> 2, part = id & 3;
            int sw = part ^ ((r >> 2) & 3);   // XOR swizzle: slot part holds chunk sw
            cp16(A + (size_t)(m0 + r) * 512 + k0 + sw * 8, als + (size_t)id * 8);
        }
        {
            int r = tid >> 2, part = tid & 3;
            int sw = part ^ ((r >> 2) & 3);
            cp16(wbf + (size_t)(o0 + r) * 512 + k0 + sw * 8, bls + (size_t)tid * 8);
        }
        __syncthreads();
        bf16x8 af[4], bfr[2];
        #pragma unroll
        for (int ms = 0; ms < 4; ms++) {
            int row = wm * 64 + ms * 16 + l15;
            int slot = quad ^ ((row >> 2) & 3);
            af[ms] = *(const bf16x8*)(als + row * 32 + slot * 8);
        }
        #pragma unroll
        for (int ns = 0; ns < 2; ns++) {
            int row = wn * 32 + ns * 16 + l15;
            int slot = quad ^ ((row >> 2) & 3);
            bfr[ns] = *(const bf16x8*)(bls + row * 32 + slot * 8);
        }
        #pragma unroll
        for (int ms = 0; ms < 4; ms++)
            #pragma unroll
            for (int ns = 0; ns < 2; ns++)
                acc[ms][ns] = __builtin_amdgcn_mfma_f32_16x16x32_bf16(af[ms], bfr[ns], acc[ms][ns], 0, 0, 0);
        __syncthreads();
    }

    int seg = o0 >> 9, lo = o0 & 511;
    if (seg < 2) {
        const float* bias = seg ? bk : bq;
        ushort_t* dst = seg ? kt : qt;
        float bv0 = bias[lo + wn * 32 + l15];
        float bv1 = bias[lo + wn * 32 + 16 + l15];
        ushort_t* cls = (ushort_t*)smem;   // [128 n][64 o]
        #pragma unroll
        for (int ms = 0; ms < 4; ms++)
            #pragma unroll
            for (int ns = 0; ns < 2; ns++)
                #pragma unroll
                for (int r = 0; r < 4; r++)
                    cls[(wm * 64 + ms * 16 + quad * 4 + r) * 64 + wn * 32 + ns * 16 + l15] =
                        f2bf(acc[ms][ns][r] + (ns ? bv1 : bv0));
        __syncthreads();
        int h = lo >> 6;
        size_t obase = ((size_t)(b * 8 + h) * 1024 + m0) * 64;
        #pragma unroll
        for (int rep = 0; rep < 4; rep++) {
            int id = rep * 256 + tid;
            int r = id >> 3, part = id & 7;
            *(uint4*)(dst + obase + (size_t)r * 64 + part * 8) = *(const uint4*)(cls + r * 64 + part * 8);
        }
    } else {
        float bv0 = bv[lo + wn * 32 + l15];
        float bv1 = bv[lo + wn * 32 + 16 + l15];
        ushort_t* clst = (ushort_t*)smem;  // [64 o][136 pad] transposed
        #pragma unroll
        for (int ms = 0; ms < 4; ms++)
            #pragma unroll
            for (int ns = 0; ns < 2; ns++)
                #pragma unroll
                for (int r = 0; r < 4; r++)
                    clst[(wn * 32 + ns * 16 + l15) * 136 + wm * 64 + ms * 16 + quad * 4 + r] =
                        f2bf(acc[ms][ns][r] + (ns ? bv1 : bv0));
        __syncthreads();
        #pragma unroll
        for (int rep = 0; rep < 4; rep++) {
            int id = rep * 256 + tid;
            int row = id >> 4, part = id & 15;   // 64 rows x 16 uint4
            *(uint4*)(vt + ((size_t)(b * 512 + lo + row) * 1024 + m0 + part * 8)) =
                *(const uint4*)(clst + row * 136 + part * 8);
        }
    }
}

// ---------------- MFMA flash attention, no-max softmax, reg-prefetched K/V ----------------
// qt/kt: [bh][n][d]; vt: [b][c][n] (== [bh][d][n]); ao: [b][n][c] bf16.
__global__ __launch_bounds__(256) void attn_kernel(const ushort_t* __restrict__ qt,
                                                   const ushort_t* __restrict__ kt,
                                                   const ushort_t* __restrict__ vt,
                                                   ushort_t* __restrict__ ao) {
    __shared__ __align__(16) ushort_t kls[64 * 72];
    __shared__ __align__(16) ushort_t vls[64 * 72];
    __shared__ __align__(16) ushort_t pls[64 * 72];
    int tid = threadIdx.x;
    int wave = tid >> 6, lane = tid & 63, l15 = lane & 15, quad = lane >> 4;
    int i0 = blockIdx.x * 64;
    int bh = blockIdx.y;
    const ushort_t* qb = qt + (size_t)bh * 65536;
    const ushort_t* kb = kt + (size_t)bh * 65536;
    const ushort_t* vb = vt + (size_t)bh * 65536;
    int iw = wave * 16;
    const float SC = 0.18033688011112042f;   // (1/8)*log2(e)

    bf16x8 qf0 = *(const bf16x8*)(qb + (size_t)(i0 + iw + l15) * 64 + quad * 8);
    bf16x8 qf1 = *(const bf16x8*)(qb + (size_t)(i0 + iw + l15) * 64 + 32 + quad * 8);

    f32x4 oacc[4];
    #pragma unroll
    for (int ds = 0; ds < 4; ds++) oacc[ds] = (f32x4){0.f, 0.f, 0.f, 0.f};
    float lacc[4] = {0.f, 0.f, 0.f, 0.f};

    int rl0 = tid >> 3, p0 = tid & 7;
    int rl1 = (256 + tid) >> 3, p1 = tid & 7;
    uint4 kr0 = *(const uint4*)(kb + (size_t)rl0 * 64 + p0 * 8);
    uint4 kr1 = *(const uint4*)(kb + (size_t)rl1 * 64 + p1 * 8);
    uint4 vr0 = *(const uint4*)(vb + (size_t)rl0 * 1024 + p0 * 8);
    uint4 vr1 = *(const uint4*)(vb + (size_t)rl1 * 1024 + p1 * 8);

    for (int jt = 0; jt < 16; jt++) {
        if (jt) __syncthreads();
        *(uint4*)(kls + rl0 * 72 + p0 * 8) = kr0;
        *(uint4*)(kls + rl1 * 72 + p1 * 8) = kr1;
        *(uint4*)(vls + rl0 * 72 + p0 * 8) = vr0;
        *(uint4*)(vls + rl1 * 72 + p1 * 8) = vr1;
        __syncthreads();
        if (jt < 15) {
            int j0n = (jt + 1) * 64;
            kr0 = *(const uint4*)(kb + (size_t)(j0n + rl0) * 64 + p0 * 8);
            kr1 = *(const uint4*)(kb + (size_t)(j0n + rl1) * 64 + p1 * 8);
            vr0 = *(const uint4*)(vb + (size_t)rl0 * 1024 + j0n + p0 * 8);
            vr1 = *(const uint4*)(vb + (size_t)rl1 * 1024 + j0n + p1 * 8);
        }

        float p[4][4];
        #pragma unroll
        for (int js = 0; js < 4; js++) {
            bf16x8 kf0 = *(const bf16x8*)(kls + (js * 16 + l15) * 72 + quad * 8);
            bf16x8 kf1 = *(const bf16x8*)(kls + (js * 16 + l15) * 72 + 32 + quad * 8);
            f32x4 z = (f32x4){0.f, 0.f, 0.f, 0.f};
            z = __builtin_amdgcn_mfma_f32_16x16x32_bf16(qf0, kf0, z, 0, 0, 0);
            z = __builtin_amdgcn_mfma_f32_16x16x32_bf16(qf1, kf1, z, 0, 0, 0);
            #pragma unroll
            for (int r = 0; r < 4; r++) p[js][r] = exp2f(z[r] * SC);
        }
        #pragma unroll
        for (int r = 0; r < 4; r++) lacc[r] += p[0][r] + p[1][r] + p[2][r] + p[3][r];
        #pragma unroll
        for (int js = 0; js < 4; js++)
            #pragma unroll
            for (int r = 0; r < 4; r++)
                pls[(iw + quad * 4 + r) * 72 + js * 16 + l15] = f2bf(p[js][r]);
        bf16x8 pa0 = *(const bf16x8*)(pls + (iw + l15) * 72 + quad * 8);
        bf16x8 pa1 = *(const bf16x8*)(pls + (iw + l15) * 72 + 32 + quad * 8);
        #pragma unroll
        for (int ds = 0; ds < 4; ds++) {
            bf16x8 vf0 = *(const bf16x8*)(vls + (ds * 16 + l15) * 72 + quad * 8);
            bf16x8 vf1 = *(const bf16x8*)(vls + (ds * 16 + l15) * 72 + 32 + quad * 8);
            oacc[ds] = __builtin_amdgcn_mfma_f32_16x16x32_bf16(pa0, vf0, oacc[ds], 0, 0, 0);
            oacc[ds] = __builtin_amdgcn_mfma_f32_16x16x32_bf16(pa1, vf1, oacc[ds], 0, 0, 0);
        }
    }

    float linv[4];
    #pragma unroll
    for (int r = 0; r < 4; r++) {
        float l = lacc[r];
        #pragma unroll
        for (int off = 8; off > 0; off >>= 1) l += __shfl_xor(l, off, 16);
        linv[r] = 1.f / l;
    }
    __syncthreads();   // all waves done reading kls before epilogue overwrite
    #pragma unroll
    for (int ds = 0; ds < 4; ds++)
        #pragma unroll
        for (int r = 0; r < 4; r++)
            kls[(iw + quad * 4 + r) * 72 + ds * 16 + l15] = f2bf(oacc[ds][r] * linv[r]);
    __syncthreads();
    int b = bh >> 3, h = bh & 7;
    ushort_t* aob = ao + ((size_t)b * 1024 + i0) * 512 + h * 64;
    #pragma unroll
    for (int rep = 0; rep < 2; rep++) {
        int id = rep * 256 + tid;
        int rl = id >> 3, part = id & 7;
        *(uint4*)(aob + (size_t)rl * 512 + part * 8) = *(const uint4*)(kls + rl * 72 + part * 8);
    }
}

// ---------------- Final conv: C[o(64)][n(64)] = Wo x ao + bo + x, fp32 out ----------------
__global__ __launch_bounds__(256) void conv_out(const ushort_t* __restrict__ ao,
                                                const ushort_t* __restrict__ wo,
                                                const float* __restrict__ bo,
                                                const float* __restrict__ xres,
                                                float* __restrict__ out) {
    __shared__ __align__(16) char smem[17408];
    ushort_t* als = (ushort_t*)smem;           // [64][32] (Wo rows o)
    ushort_t* bls = (ushort_t*)(smem + 4096);  // [64][32] (ao rows n)
    int tid = threadIdx.x;
    int wave = tid >> 6, lane = tid & 63, l15 = lane & 15, quad = lane >> 4;
    int wm = wave >> 1, wn = wave & 1;
    int m0 = blockIdx.x * 64, n0 = blockIdx.y * 64, b = blockIdx.z;
    const ushort_t* B = ao + (size_t)b * 524288;

    f32x4 acc[2][2];
    #pragma unroll
    for (int ms = 0; ms < 2; ms++)
        #pragma unroll
        for (int ns = 0; ns < 2; ns++) acc[ms][ns] = (f32x4){0.f, 0.f, 0.f, 0.f};

    for (int k0 = 0; k0 < 512; k0 += 32) {
        {
            int r = tid >> 2, part = tid & 3;
            int sw = part ^ ((r >> 2) & 3);
            cp16(wo + (size_t)(m0 + r) * 512 + k0 + sw * 8, als + (size_t)tid * 8);
            cp16(B + (size_t)(n0 + r) * 512 + k0 + sw * 8, bls + (size_t)tid * 8);
        }
        __syncthreads();
        bf16x8 af[2], bfr[2];
        #pragma unroll
        for (int ms = 0; ms < 2; ms++) {
            int row = wm * 32 + ms * 16 + l15;
            int slot = quad ^ ((row >> 2) & 3);
            af[ms] = *(const bf16x8*)(als + row * 32 + slot * 8);
        }
        #pragma unroll
        for (int ns = 0; ns < 2; ns++) {
            int row = wn * 32 + ns * 16 + l15;
            int slot = quad ^ ((row >> 2) & 3);
            bfr[ns] = *(const bf16x8*)(bls + row * 32 + slot * 8);
        }
        #pragma unroll
        for (int ms = 0; ms < 2; ms++)
            #pragma unroll
            for (int ns = 0; ns < 2; ns++)
                acc[ms][ns] = __builtin_amdgcn_mfma_f32_16x16x32_bf16(af[ms], bfr[ns], acc[ms][ns], 0, 0, 0);
        __syncthreads();
    }

    float* clsf = (float*)smem;   // [64 o][68 pad] fp32
    #pragma unroll
    for (int ms = 0; ms < 2; ms++)
        #pragma unroll
        for (int ns = 0; ns < 2; ns++)
            #pragma unroll
            for (int r = 0; r < 4; r++)
                clsf[(wm * 32 + ms * 16 + quad * 4 + r) * 68 + wn * 32 + ns * 16 + l15] = acc[ms][ns][r];
    __syncthreads();
    #pragma unroll
    for (int rep = 0; rep < 4; rep++) {
        int id = rep * 256 + tid;
        int row = id >> 4, part = id & 15;
        float bvr = bo[m0 + row];
        float4 c4 = *(const float4*)(clsf + row * 68 + part * 4);
        size_t ga = ((size_t)(b * 512 + m0 + row)) * 1024 + n0 + part * 4;
        float4 xv = *(const float4*)(xres + ga);
        c4.x += bvr + xv.x; c4.y += bvr + xv.y; c4.z += bvr + xv.z; c4.w += bvr + xv.w;
        *(float4*)(out + ga) = c4;
    }
}

extern "C" void kernel_launch(void* const* d_in, const int* in_sizes, int n_in,
                              void* d_out, int out_size, void* d_ws, size_t ws_size,
                              hipStream_t stream) {
    const float* x    = (const float*)d_in[0];
    const float* gn_w = (const float*)d_in[1];
    const float* gn_b = (const float*)d_in[2];
    const float* wq   = (const float*)d_in[3];
    const float* bq   = (const float*)d_in[4];
    const float* wk   = (const float*)d_in[5];
    const float* bk   = (const float*)d_in[6];
    const float* wv   = (const float*)d_in[7];
    const float* bv   = (const float*)d_in[8];
    const float* wo   = (const float*)d_in[9];
    const float* bo   = (const float*)d_in[10];

    char* ws = (char*)d_ws;
    ushort_t* xnt  = (ushort_t*)(ws);                        // 8 MB  [b][n][c]
    ushort_t* qt   = (ushort_t*)(ws + (((size_t)8)  << 20)); // 8 MB  [bh][n][d]
    ushort_t* kt   = (ushort_t*)(ws + (((size_t)16) << 20)); // 8 MB  [bh][n][d]
    ushort_t* vt   = (ushort_t*)(ws + (((size_t)24) << 20)); // 8 MB  [b][c][n]
    ushort_t* wbf  = (ushort_t*)(ws + (((size_t)32) << 20)); // 2 MB  Wq|Wk|Wv|Wo bf16
    float2*   gst  = (float2*)  (ws + (((size_t)34) << 20)); // 2 KB  stats
    ushort_t* ao   = xnt;   // attn output reuses xnt (read fully before attn)

    wcvt_kernel<<<dim3(256, 4), 256, 0, stream>>>(wq, wk, wv, wo, wbf);
    gn_stats<<<256, 256, 0, stream>>>(x, gst);
    gn_apply<<<dim3(4, 256), 256, 0, stream>>>(x, gn_w, gn_b, gst, xnt);

    conv_qkv<<<dim3(8, 24, 8), 256, 0, stream>>>(xnt, wbf, bq, bk, bv, qt, kt, vt);

    attn_kernel<<<dim3(16, 64), 256, 0, stream>>>(qt, kt, vt, ao);

    conv_out<<<dim3(8, 16, 8), 256, 0, stream>>>(ao, wbf + 786432, bo, x, (float*)d_out);
}

// Round 7
// 176.729 us; speedup vs baseline: 4.5872x; 1.0213x over previous
//
#include <hip/hip_runtime.h>
#include <hip/hip_bf16.h>

typedef unsigned short ushort_t;
typedef __bf16 bf16_t;
typedef bf16_t bf16x8 __attribute__((ext_vector_type(8)));
typedef float f32x4 __attribute__((ext_vector_type(4)));

#define CH 512
#define NSP 1024  // H*W

__device__ __forceinline__ float bf2f(ushort_t u) {
    union { unsigned int i; float f; } t; t.i = ((unsigned int)u) << 16; return t.f;
}
__device__ __forceinline__ ushort_t f2bf(float f) {
    union { float fl; unsigned int i; } t; t.fl = f;
    unsigned int r = t.i + 0x7fffu + ((t.i >> 16) & 1u);  // RNE
    return (ushort_t)(r >> 16);
}
// packed RNE f32x2 -> bf16x2 (v_cvt_pk_bf16_f32 on gfx950)
__device__ __forceinline__ unsigned int pk2(float a, float b) {
    __hip_bfloat162 h = __float22bfloat162_rn(make_float2(a, b));
    union { __hip_bfloat162 h2; unsigned int u; } t; t.h2 = h; return t.u;
}

#if __has_builtin(__builtin_amdgcn_global_load_lds)
#define HAVE_ASYNC_LDS 1
#endif
__device__ __forceinline__ void cp16(const ushort_t* g, ushort_t* l) {
#ifdef HAVE_ASYNC_LDS
    __builtin_amdgcn_global_load_lds((const __attribute__((address_space(1))) unsigned int*)g,
                                     (__attribute__((address_space(3))) unsigned int*)l, 16, 0, 0);
#else
    *(uint4*)l = *(const uint4*)g;
#endif
}

#define QSCALE 0.18033688011112042f   // 0.125 * log2(e), folded into q

// ---------------- prep: blocks 0..255 = GN stats; 256..1279 = W fp32->bf16 ----------------
__global__ __launch_bounds__(256) void prep_kernel(const float* __restrict__ x,
                                                   const float* __restrict__ w0, const float* __restrict__ w1,
                                                   const float* __restrict__ w2, const float* __restrict__ w3,
                                                   float2* __restrict__ gstats, ushort_t* __restrict__ wbf) {
    int tid = threadIdx.x;
    if (blockIdx.x >= 256) {
        int idx = (blockIdx.x - 256) * 256 + tid;   // 0..262143 float4s
        int my = idx >> 16;
        const float* src = (my == 0) ? w0 : (my == 1) ? w1 : (my == 2) ? w2 : w3;
        float4 v = reinterpret_cast<const float4*>(src)[idx & 65535];
        uint2 u = make_uint2(pk2(v.x, v.y), pk2(v.z, v.w));
        reinterpret_cast<uint2*>(wbf + (size_t)my * 262144)[idx & 65535] = u;
        return;
    }
    __shared__ float red[8];
    int bg = blockIdx.x;
    size_t base = (size_t)bg * 16384;
    float s = 0.f, s2 = 0.f;
    const float4* x4 = reinterpret_cast<const float4*>(x + base);
    for (int i = tid; i < 4096; i += 256) {
        float4 v = x4[i];
        s  += v.x + v.y + v.z + v.w;
        s2 += v.x * v.x + v.y * v.y + v.z * v.z + v.w * v.w;
    }
    #pragma unroll
    for (int off = 32; off > 0; off >>= 1) {
        s  += __shfl_down(s, off, 64);
        s2 += __shfl_down(s2, off, 64);
    }
    int wv = tid >> 6;
    if ((tid & 63) == 0) { red[wv] = s; red[4 + wv] = s2; }
    __syncthreads();
    if (tid == 0) {
        float ts  = red[0] + red[1] + red[2] + red[3];
        float ts2 = red[4] + red[5] + red[6] + red[7];
        float mu  = ts * (1.f / 16384.f);
        float var = ts2 * (1.f / 16384.f) - mu * mu;
        gstats[bg] = make_float2(mu, rsqrtf(var + 1e-5f));
    }
}

// ---------------- GroupNorm apply + transpose -> xnt [b][n][c] bf16 ----------------
__global__ __launch_bounds__(256) void gn_apply(const float* __restrict__ x, const float* __restrict__ gw,
                                                const float* __restrict__ gbias, const float2* __restrict__ gstats,
                                                ushort_t* __restrict__ xnt) {
    __shared__ __align__(16) ushort_t lt[16 * 264];
    int nq = blockIdx.x;            // 0..3 (256-col chunk)
    int bg = blockIdx.y;            // b*32+g
    int b = bg >> 5, g = bg & 31;
    int tid = threadIdx.x;
    float2 st = gstats[bg];
    float mu = st.x, rstd = st.y;
    const float4* x4 = reinterpret_cast<const float4*>(x + ((size_t)(b * 512 + g * 16) * 1024 + nq * 256));
    #pragma unroll
    for (int rep = 0; rep < 4; rep++) {
        int id = rep * 256 + tid;
        int cc = id >> 6, j = id & 63;
        float ww = gw[g * 16 + cc], bb = gbias[g * 16 + cc];
        float ca = rstd * ww, cb = bb - mu * ca;
        float4 v = x4[cc * 256 + j];
        uint2 u = make_uint2(pk2(v.x * ca + cb, v.y * ca + cb), pk2(v.z * ca + cb, v.w * ca + cb));
        *reinterpret_cast<uint2*>(&lt[cc * 264 + j * 4]) = u;
    }
    __syncthreads();
    int n = tid;
    ushort_t ov[16];
    #pragma unroll
    for (int cc = 0; cc < 16; cc++) ov[cc] = lt[cc * 264 + n];
    ushort_t* dst = xnt + ((size_t)(b * 1024 + nq * 256 + n)) * 512 + g * 16;
    *reinterpret_cast<ushort4*>(dst + 0)  = *reinterpret_cast<ushort4*>(&ov[0]);
    *reinterpret_cast<ushort4*>(dst + 4)  = *reinterpret_cast<ushort4*>(&ov[4]);
    *reinterpret_cast<ushort4*>(dst + 8)  = *reinterpret_cast<ushort4*>(&ov[8]);
    *reinterpret_cast<ushort4*>(dst + 12) = *reinterpret_cast<ushort4*>(&ov[12]);
}

// ---------------- Fused QKV conv: C[n_sp(128)][o(64)] tiles, o in 0..1535 ----------------
__global__ __launch_bounds__(256) void conv_qkv(const ushort_t* __restrict__ xnt,
                                                const ushort_t* __restrict__ wbf,
                                                const float* __restrict__ bq,
                                                const float* __restrict__ bk,
                                                const float* __restrict__ bv,
                                                ushort_t* __restrict__ qt,
                                                ushort_t* __restrict__ kt,
                                                ushort_t* __restrict__ vt) {
    __shared__ __align__(16) char smem[17408];
    ushort_t* als = (ushort_t*)smem;           // [128][32]
    ushort_t* bls = (ushort_t*)(smem + 8192);  // [64][32]
    int tid = threadIdx.x;
    int wave = tid >> 6, lane = tid & 63, l15 = lane & 15, quad = lane >> 4;
    int wm = wave >> 1, wn = wave & 1;
    int m0 = blockIdx.x * 128, o0 = blockIdx.y * 64, b = blockIdx.z;
    const ushort_t* A = xnt + (size_t)b * 524288;

    f32x4 acc[4][2];
    #pragma unroll
    for (int ms = 0; ms < 4; ms++)
        #pragma unroll
        for (int ns = 0; ns < 2; ns++) acc[ms][ns] = (f32x4){0.f, 0.f, 0.f, 0.f};

    for (int k0 = 0; k0 < 512; k0 += 32) {
        #pragma unroll
        for (int rep = 0; rep < 2; rep++) {
            int id = rep * 256 + tid;
            int r = id >> 2, part = id & 3;
            int sw = part ^ ((r >> 2) & 3);
            cp16(A + (size_t)(m0 + r) * 512 + k0 + sw * 8, als + (size_t)id * 8);
        }
        {
            int r = tid >> 2, part = tid & 3;
            int sw = part ^ ((r >> 2) & 3);
            cp16(wbf + (size_t)(o0 + r) * 512 + k0 + sw * 8, bls + (size_t)tid * 8);
        }
        __syncthreads();
        bf16x8 af[4], bfr[2];
        #pragma unroll
        for (int ms = 0; ms < 4; ms++) {
            int row = wm * 64 + ms * 16 + l15;
            int slot = quad ^ ((row >> 2) & 3);
            af[ms] = *(const bf16x8*)(als + row * 32 + slot * 8);
        }
        #pragma unroll
        for (int ns = 0; ns < 2; ns++) {
            int row = wn * 32 + ns * 16 + l15;
            int slot = quad ^ ((row >> 2) & 3);
            bfr[ns] = *(const bf16x8*)(bls + row * 32 + slot * 8);
        }
        #pragma unroll
        for (int ms = 0; ms < 4; ms++)
            #pragma unroll
            for (int ns = 0; ns < 2; ns++)
                acc[ms][ns] = __builtin_amdgcn_mfma_f32_16x16x32_bf16(af[ms], bfr[ns], acc[ms][ns], 0, 0, 0);
        __syncthreads();
    }

    int seg = o0 >> 9, lo = o0 & 511;
    if (seg < 2) {
        const float* bias = seg ? bk : bq;
        ushort_t* dst = seg ? kt : qt;
        float s = seg ? 1.f : QSCALE;
        float bv0 = bias[lo + wn * 32 + l15];
        float bv1 = bias[lo + wn * 32 + 16 + l15];
        ushort_t* cls = (ushort_t*)smem;   // [128 n][64 o]
        #pragma unroll
        for (int ms = 0; ms < 4; ms++)
            #pragma unroll
            for (int ns = 0; ns < 2; ns++) {
                float bb = ns ? bv1 : bv0;
                int idx = (wm * 64 + ms * 16 + quad * 4) * 64 + wn * 32 + ns * 16 + l15;
                unsigned int ua = pk2((acc[ms][ns][0] + bb) * s, (acc[ms][ns][1] + bb) * s);
                unsigned int ub = pk2((acc[ms][ns][2] + bb) * s, (acc[ms][ns][3] + bb) * s);
                cls[idx]       = (ushort_t)(ua & 0xffff);
                cls[idx + 64]  = (ushort_t)(ua >> 16);
                cls[idx + 128] = (ushort_t)(ub & 0xffff);
                cls[idx + 192] = (ushort_t)(ub >> 16);
            }
        __syncthreads();
        int h = lo >> 6;
        size_t obase = ((size_t)(b * 8 + h) * 1024 + m0) * 64;
        #pragma unroll
        for (int rep = 0; rep < 4; rep++) {
            int id = rep * 256 + tid;
            int r = id >> 3, part = id & 7;
            *(uint4*)(dst + obase + (size_t)r * 64 + part * 8) = *(const uint4*)(cls + r * 64 + part * 8);
        }
    } else {
        float bv0 = bv[lo + wn * 32 + l15];
        float bv1 = bv[lo + wn * 32 + 16 + l15];
        ushort_t* clst = (ushort_t*)smem;  // [64 o][136] transposed
        #pragma unroll
        for (int ms = 0; ms < 4; ms++)
            #pragma unroll
            for (int ns = 0; ns < 2; ns++) {
                float bb = ns ? bv1 : bv0;
                unsigned int ua = pk2(acc[ms][ns][0] + bb, acc[ms][ns][1] + bb);
                unsigned int ub = pk2(acc[ms][ns][2] + bb, acc[ms][ns][3] + bb);
                *(uint2*)(&clst[(wn * 32 + ns * 16 + l15) * 136 + wm * 64 + ms * 16 + quad * 4]) =
                    make_uint2(ua, ub);
            }
        __syncthreads();
        #pragma unroll
        for (int rep = 0; rep < 4; rep++) {
            int id = rep * 256 + tid;
            int row = id >> 4, part = id & 15;
            *(uint4*)(vt + ((size_t)(b * 512 + lo + row) * 1024 + m0 + part * 8)) =
                *(const uint4*)(clst + row * 136 + part * 8);
        }
    }
}

// ---------------- MFMA flash attention: S^T trick, packed cvt, XCD-swizzled grid ----------------
// qt (pre-scaled by QSCALE)/kt: [bh][n][d]; vt: [bh][d][n]; ao: [b][n][c] bf16.
__global__ __launch_bounds__(256) void attn_kernel(const ushort_t* __restrict__ qt,
                                                   const ushort_t* __restrict__ kt,
                                                   const ushort_t* __restrict__ vt,
                                                   ushort_t* __restrict__ ao) {
    __shared__ __align__(16) ushort_t kls[64 * 72];
    __shared__ __align__(16) ushort_t vls[64 * 72];
    __shared__ __align__(16) ushort_t pls[64 * 88];   // stride 88: b64 writes conflict-free
    int tid = threadIdx.x;
    int wave = tid >> 6, lane = tid & 63, l15 = lane & 15, quad = lane >> 4;
    int id = blockIdx.x;                    // XCD swizzle: each XCD sees only 8 bh
    int sub = id >> 3;
    int bh = (id & 7) * 8 + (sub >> 4);
    int i0 = (sub & 15) * 64;
    const ushort_t* qb = qt + (size_t)bh * 65536;
    const ushort_t* kb = kt + (size_t)bh * 65536;
    const ushort_t* vb = vt + (size_t)bh * 65536;
    int iw = wave * 16;

    bf16x8 qf0 = *(const bf16x8*)(qb + (size_t)(i0 + iw + l15) * 64 + quad * 8);
    bf16x8 qf1 = *(const bf16x8*)(qb + (size_t)(i0 + iw + l15) * 64 + 32 + quad * 8);

    f32x4 oacc[4];
    #pragma unroll
    for (int ds = 0; ds < 4; ds++) oacc[ds] = (f32x4){0.f, 0.f, 0.f, 0.f};
    float lacc = 0.f;                       // this thread's i = iw + l15

    int rl0 = tid >> 3, p0 = tid & 7;
    int rl1 = 32 + rl0;
    uint4 kr0 = *(const uint4*)(kb + (size_t)rl0 * 64 + p0 * 8);
    uint4 kr1 = *(const uint4*)(kb + (size_t)rl1 * 64 + p0 * 8);
    uint4 vr0 = *(const uint4*)(vb + (size_t)rl0 * 1024 + p0 * 8);
    uint4 vr1 = *(const uint4*)(vb + (size_t)rl1 * 1024 + p0 * 8);

    for (int jt = 0; jt < 16; jt++) {
        if (jt) __syncthreads();
        *(uint4*)(kls + rl0 * 72 + p0 * 8) = kr0;
        *(uint4*)(kls + rl1 * 72 + p0 * 8) = kr1;
        *(uint4*)(vls + rl0 * 72 + p0 * 8) = vr0;
        *(uint4*)(vls + rl1 * 72 + p0 * 8) = vr1;
        __syncthreads();
        if (jt < 15) {
            int j0n = (jt + 1) * 64;
            kr0 = *(const uint4*)(kb + (size_t)(j0n + rl0) * 64 + p0 * 8);
            kr1 = *(const uint4*)(kb + (size_t)(j0n + rl1) * 64 + p0 * 8);
            vr0 = *(const uint4*)(vb + (size_t)rl0 * 1024 + j0n + p0 * 8);
            vr1 = *(const uint4*)(vb + (size_t)rl1 * 1024 + j0n + p0 * 8);
        }

        // S^T: mfma(K, Q) -> thread holds S[j = js*16+quad*4+r][i = iw+l15]
        #pragma unroll
        for (int js = 0; js < 4; js++) {
            bf16x8 kf0 = *(const bf16x8*)(kls + (js * 16 + l15) * 72 + quad * 8);
            bf16x8 kf1 = *(const bf16x8*)(kls + (js * 16 + l15) * 72 + 32 + quad * 8);
            f32x4 z = (f32x4){0.f, 0.f, 0.f, 0.f};
            z = __builtin_amdgcn_mfma_f32_16x16x32_bf16(kf0, qf0, z, 0, 0, 0);
            z = __builtin_amdgcn_mfma_f32_16x16x32_bf16(kf1, qf1, z, 0, 0, 0);
            float e0 = exp2f(z[0]), e1 = exp2f(z[1]), e2 = exp2f(z[2]), e3 = exp2f(z[3]);
            lacc += (e0 + e1) + (e2 + e3);
            *(uint2*)(pls + (iw + l15) * 88 + js * 16 + quad * 4) =
                make_uint2(pk2(e0, e1), pk2(e2, e3));
        }
        bf16x8 pa0 = *(const bf16x8*)(pls + (iw + l15) * 88 + quad * 8);
        bf16x8 pa1 = *(const bf16x8*)(pls + (iw + l15) * 88 + 32 + quad * 8);
        #pragma unroll
        for (int ds = 0; ds < 4; ds++) {
            bf16x8 vf0 = *(const bf16x8*)(vls + (ds * 16 + l15) * 72 + quad * 8);
            bf16x8 vf1 = *(const bf16x8*)(vls + (ds * 16 + l15) * 72 + 32 + quad * 8);
            oacc[ds] = __builtin_amdgcn_mfma_f32_16x16x32_bf16(pa0, vf0, oacc[ds], 0, 0, 0);
            oacc[ds] = __builtin_amdgcn_mfma_f32_16x16x32_bf16(pa1, vf1, oacc[ds], 0, 0, 0);
        }
    }

    // full l for i = iw + l15, then redistribute to C-layout rows (i = iw + quad*4 + r)
    lacc += __shfl_xor(lacc, 16, 64);
    lacc += __shfl_xor(lacc, 32, 64);
    float linv[4];
    #pragma unroll
    for (int r = 0; r < 4; r++) linv[r] = 1.f / __shfl(lacc, quad * 4 + r, 64);

    __syncthreads();   // all waves done with kls before epilogue reuse
    #pragma unroll
    for (int ds = 0; ds < 4; ds++)
        #pragma unroll
        for (int r = 0; r < 4; r++)
            kls[(iw + quad * 4 + r) * 72 + ds * 16 + l15] = f2bf(oacc[ds][r] * linv[r]);
    __syncthreads();
    int b = bh >> 3, h = bh & 7;
    ushort_t* aob = ao + ((size_t)b * 1024 + i0) * 512 + h * 64;
    #pragma unroll
    for (int rep = 0; rep < 2; rep++) {
        int idd = rep * 256 + tid;
        int rl = idd >> 3, part = idd & 7;
        *(uint4*)(aob + (size_t)rl * 512 + part * 8) = *(const uint4*)(kls + rl * 72 + part * 8);
    }
}

// ---------------- Final conv: C[o(64)][n(64)] = Wo x ao + bo + x, fp32 out ----------------
__global__ __launch_bounds__(256) void conv_out(const ushort_t* __restrict__ ao,
                                                const ushort_t* __restrict__ wo,
                                                const float* __restrict__ bo,
                                                const float* __restrict__ xres,
                                                float* __restrict__ out) {
    __shared__ __align__(16) char smem[17408];
    ushort_t* als = (ushort_t*)smem;           // [64][32]
    ushort_t* bls = (ushort_t*)(smem + 4096);  // [64][32]
    int tid = threadIdx.x;
    int wave = tid >> 6, lane = tid & 63, l15 = lane & 15, quad = lane >> 4;
    int wm = wave >> 1, wn = wave & 1;
    int m0 = blockIdx.x * 64, n0 = blockIdx.y * 64, b = blockIdx.z;
    const ushort_t* B = ao + (size_t)b * 524288;

    f32x4 acc[2][2];
    #pragma unroll
    for (int ms = 0; ms < 2; ms++)
        #pragma unroll
        for (int ns = 0; ns < 2; ns++) acc[ms][ns] = (f32x4){0.f, 0.f, 0.f, 0.f};

    for (int k0 = 0; k0 < 512; k0 += 32) {
        {
            int r = tid >> 2, part = tid & 3;
            int sw = part ^ ((r >> 2) & 3);
            cp16(wo + (size_t)(m0 + r) * 512 + k0 + sw * 8, als + (size_t)tid * 8);
            cp16(B + (size_t)(n0 + r) * 512 + k0 + sw * 8, bls + (size_t)tid * 8);
        }
        __syncthreads();
        bf16x8 af[2], bfr[2];
        #pragma unroll
        for (int ms = 0; ms < 2; ms++) {
            int row = wm * 32 + ms * 16 + l15;
            int slot = quad ^ ((row >> 2) & 3);
            af[ms] = *(const bf16x8*)(als + row * 32 + slot * 8);
        }
        #pragma unroll
        for (int ns = 0; ns < 2; ns++) {
            int row = wn * 32 + ns * 16 + l15;
            int slot = quad ^ ((row >> 2) & 3);
            bfr[ns] = *(const bf16x8*)(bls + row * 32 + slot * 8);
        }
        #pragma unroll
        for (int ms = 0; ms < 2; ms++)
            #pragma unroll
            for (int ns = 0; ns < 2; ns++)
                acc[ms][ns] = __builtin_amdgcn_mfma_f32_16x16x32_bf16(af[ms], bfr[ns], acc[ms][ns], 0, 0, 0);
        __syncthreads();
    }

    float* clsf = (float*)smem;   // [64 o][68]
    #pragma unroll
    for (int ms = 0; ms < 2; ms++)
        #pragma unroll
        for (int ns = 0; ns < 2; ns++)
            #pragma unroll
            for (int r = 0; r < 4; r++)
                clsf[(wm * 32 + ms * 16 + quad * 4 + r) * 68 + wn * 32 + ns * 16 + l15] = acc[ms][ns][r];
    __syncthreads();
    #pragma unroll
    for (int rep = 0; rep < 4; rep++) {
        int id = rep * 256 + tid;
        int row = id >> 4, part = id & 15;
        float bvr = bo[m0 + row];
        float4 c4 = *(const float4*)(clsf + row * 68 + part * 4);
        size_t ga = ((size_t)(b * 512 + m0 + row)) * 1024 + n0 + part * 4;
        float4 xv = *(const float4*)(xres + ga);
        c4.x += bvr + xv.x; c4.y += bvr + xv.y; c4.z += bvr + xv.z; c4.w += bvr + xv.w;
        *(float4*)(out + ga) = c4;
    }
}

extern "C" void kernel_launch(void* const* d_in, const int* in_sizes, int n_in,
                              void* d_out, int out_size, void* d_ws, size_t ws_size,
                              hipStream_t stream) {
    const float* x    = (const float*)d_in[0];
    const float* gn_w = (const float*)d_in[1];
    const float* gn_b = (const float*)d_in[2];
    const float* wq   = (const float*)d_in[3];
    const float* bq   = (const float*)d_in[4];
    const float* wk   = (const float*)d_in[5];
    const float* bk   = (const float*)d_in[6];
    const float* wv   = (const float*)d_in[7];
    const float* bv   = (const float*)d_in[8];
    const float* wo   = (const float*)d_in[9];
    const float* bo   = (const float*)d_in[10];

    char* ws = (char*)d_ws;
    ushort_t* xnt  = (ushort_t*)(ws);                        // 8 MB  [b][n][c]
    ushort_t* qt   = (ushort_t*)(ws + (((size_t)8)  << 20)); // 8 MB  [bh][n][d] (pre-scaled)
    ushort_t* kt   = (ushort_t*)(ws + (((size_t)16) << 20)); // 8 MB  [bh][n][d]
    ushort_t* vt   = (ushort_t*)(ws + (((size_t)24) << 20)); // 8 MB  [b][c][n]
    ushort_t* wbf  = (ushort_t*)(ws + (((size_t)32) << 20)); // 2 MB  Wq|Wk|Wv|Wo bf16
    float2*   gst  = (float2*)  (ws + (((size_t)34) << 20)); // 2 KB  stats
    ushort_t* ao   = xnt;   // attn output reuses xnt

    prep_kernel<<<1280, 256, 0, stream>>>(x, wq, wk, wv, wo, gst, wbf);
    gn_apply<<<dim3(4, 256), 256, 0, stream>>>(x, gn_w, gn_b, gst, xnt);

    conv_qkv<<<dim3(8, 24, 8), 256, 0, stream>>>(xnt, wbf, bq, bk, bv, qt, kt, vt);

    attn_kernel<<<1024, 256, 0, stream>>>(qt, kt, vt, ao);

    conv_out<<<dim3(8, 16, 8), 256, 0, stream>>>(ao, wbf + 786432, bo, x, (float*)d_out);
}